// Round 1
// baseline (917.045 us; speedup 1.0000x reference)
//
#include <hip/hip_runtime.h>
#include <math.h>

#define B_ 32
#define L_ 512
#define D_ 512
#define H_ 512

// ---------------------------------------------------------------------------
// Tiled fp32 GEMM building blocks: 64x64 block tile, 16x16 threads, 4x4/thread
// (strided by 16 to keep LDS reads broadcast/conflict-free), BK=16,
// LDS tiles padded to 65 to break power-of-2 bank strides.
// ---------------------------------------------------------------------------

// S[b,i,j] = sum_d I[b,i,d] * J[b,j,d]
__global__ __launch_bounds__(256) void score_kernel(const float* __restrict__ I,
                                                    const float* __restrict__ Jm,
                                                    float* __restrict__ S) {
    const int b = blockIdx.z;
    const int i0 = blockIdx.y * 64;
    const int j0 = blockIdx.x * 64;
    const float* Ib = I + (size_t)b * L_ * D_;
    const float* Jb = Jm + (size_t)b * L_ * D_;
    float* Sb = S + (size_t)b * L_ * L_;

    __shared__ float As[16][65];
    __shared__ float Bs[16][65];
    const int tx = threadIdx.x, ty = threadIdx.y;
    const int tid = ty * 16 + tx;
    float acc[4][4] = {};

    for (int k0 = 0; k0 < D_; k0 += 16) {
#pragma unroll
        for (int m = 0; m < 4; ++m) {
            int e = m * 256 + tid;
            int r = e >> 4, kk = e & 15;              // r in [0,64), kk in [0,16)
            As[kk][r] = Ib[(size_t)(i0 + r) * D_ + k0 + kk];
            Bs[kk][r] = Jb[(size_t)(j0 + r) * D_ + k0 + kk];
        }
        __syncthreads();
#pragma unroll
        for (int k = 0; k < 16; ++k) {
            float a[4], bv[4];
#pragma unroll
            for (int m = 0; m < 4; ++m) a[m] = As[k][ty + m * 16];
#pragma unroll
            for (int n = 0; n < 4; ++n) bv[n] = Bs[k][tx + n * 16];
#pragma unroll
            for (int m = 0; m < 4; ++m)
#pragma unroll
                for (int n = 0; n < 4; ++n) acc[m][n] = fmaf(a[m], bv[n], acc[m][n]);
        }
        __syncthreads();
    }
#pragma unroll
    for (int m = 0; m < 4; ++m) {
        int i = i0 + ty + m * 16;
#pragma unroll
        for (int n = 0; n < 4; ++n) {
            int j = j0 + tx + n * 16;
            Sb[(size_t)i * L_ + j] = acc[m][n];
        }
    }
}

// per-(b,i): rmax = max_j S, rsum = sum_j exp(S - rmax)
__global__ __launch_bounds__(256) void row_stats_kernel(const float* __restrict__ S,
                                                        float* __restrict__ rmax,
                                                        float* __restrict__ rsum) {
    const int row = blockIdx.x;  // b*L_ + i
    const float* Sr = S + (size_t)row * L_;
    const int t = threadIdx.x;
    float v1 = Sr[t], v2 = Sr[t + 256];
    __shared__ float red[256];
    red[t] = fmaxf(v1, v2);
    __syncthreads();
    for (int s = 128; s > 0; s >>= 1) {
        if (t < s) red[t] = fmaxf(red[t], red[t + s]);
        __syncthreads();
    }
    const float mx = red[0];
    __syncthreads();
    red[t] = __expf(v1 - mx) + __expf(v2 - mx);
    __syncthreads();
    for (int s = 128; s > 0; s >>= 1) {
        if (t < s) red[t] += red[t + s];
        __syncthreads();
    }
    if (t == 0) {
        rmax[row] = mx;
        rsum[row] = red[0];
    }
}

// per-(b,j): cmax = max_i S, csum = sum_i exp(S - cmax)
__global__ __launch_bounds__(256) void col_stats_kernel(const float* __restrict__ S,
                                                        float* __restrict__ cmax,
                                                        float* __restrict__ csum) {
    const int b = blockIdx.z;
    const int j = blockIdx.x * 32 + threadIdx.x;
    const float* Sb = S + (size_t)b * L_ * L_;
    __shared__ float redm[8][32];
    __shared__ float reds[8][32];

    float m = -1e30f;
    for (int i = threadIdx.y; i < L_; i += 8) m = fmaxf(m, Sb[(size_t)i * L_ + j]);
    redm[threadIdx.y][threadIdx.x] = m;
    __syncthreads();
    if (threadIdx.y == 0) {
#pragma unroll
        for (int r = 1; r < 8; ++r) m = fmaxf(m, redm[r][threadIdx.x]);
        redm[0][threadIdx.x] = m;
    }
    __syncthreads();
    m = redm[0][threadIdx.x];

    float s = 0.f;
    for (int i = threadIdx.y; i < L_; i += 8) s += __expf(Sb[(size_t)i * L_ + j] - m);
    reds[threadIdx.y][threadIdx.x] = s;
    __syncthreads();
    if (threadIdx.y == 0) {
#pragma unroll
        for (int r = 1; r < 8; ++r) s += reds[r][threadIdx.x];
        cmax[b * L_ + j] = m;
        csum[b * L_ + j] = s;
    }
}

// Xi[b,i,d] = | I[b,i,d] - sum_j softmax_row(S)[i,j] * J[b,j,d] |
__global__ __launch_bounds__(256) void wj_kernel(const float* __restrict__ S,
                                                 const float* __restrict__ Jm,
                                                 const float* __restrict__ I,
                                                 const float* __restrict__ rmax,
                                                 const float* __restrict__ rsum,
                                                 float* __restrict__ Xi) {
    const int b = blockIdx.z;
    const int i0 = blockIdx.y * 64;
    const int d0 = blockIdx.x * 64;
    const float* Sb = S + (size_t)b * L_ * L_;
    const float* Jb = Jm + (size_t)b * L_ * D_;
    const float* Ib = I + (size_t)b * L_ * D_;

    __shared__ float As[16][65];
    __shared__ float Bs[16][65];
    __shared__ float rmx[64], rsm[64];
    const int tx = threadIdx.x, ty = threadIdx.y;
    const int tid = ty * 16 + tx;
    if (tid < 64) {
        rmx[tid] = rmax[b * L_ + i0 + tid];
        rsm[tid] = 1.0f / rsum[b * L_ + i0 + tid];
    }
    __syncthreads();

    float acc[4][4] = {};
    for (int k0 = 0; k0 < L_; k0 += 16) {
#pragma unroll
        for (int m = 0; m < 4; ++m) {
            int e = m * 256 + tid;
            {
                int ii = e >> 4, kk = e & 15;
                As[kk][ii] = __expf(Sb[(size_t)(i0 + ii) * L_ + k0 + kk] - rmx[ii]);
            }
            {
                int kk = e >> 6, dd = e & 63;
                Bs[kk][dd] = Jb[(size_t)(k0 + kk) * D_ + d0 + dd];
            }
        }
        __syncthreads();
#pragma unroll
        for (int k = 0; k < 16; ++k) {
            float a[4], bv[4];
#pragma unroll
            for (int m = 0; m < 4; ++m) a[m] = As[k][ty + m * 16];
#pragma unroll
            for (int n = 0; n < 4; ++n) bv[n] = Bs[k][tx + n * 16];
#pragma unroll
            for (int m = 0; m < 4; ++m)
#pragma unroll
                for (int n = 0; n < 4; ++n) acc[m][n] = fmaf(a[m], bv[n], acc[m][n]);
        }
        __syncthreads();
    }
#pragma unroll
    for (int m = 0; m < 4; ++m) {
        int i = i0 + ty + m * 16;
        float inv = rsm[ty + m * 16];
#pragma unroll
        for (int n = 0; n < 4; ++n) {
            int d = d0 + tx + n * 16;
            float wv = acc[m][n] * inv;
            Xi[(size_t)b * L_ * D_ + (size_t)i * D_ + d] = fabsf(Ib[(size_t)i * D_ + d] - wv);
        }
    }
}

// Xj[b,j,d] = | J[b,j,d] - sum_i softmax_col(S)[i,j] * I[b,i,d] |
__global__ __launch_bounds__(256) void wi_kernel(const float* __restrict__ S,
                                                 const float* __restrict__ I,
                                                 const float* __restrict__ Jm,
                                                 const float* __restrict__ cmax,
                                                 const float* __restrict__ csum,
                                                 float* __restrict__ Xj) {
    const int b = blockIdx.z;
    const int j0 = blockIdx.y * 64;
    const int d0 = blockIdx.x * 64;
    const float* Sb = S + (size_t)b * L_ * L_;
    const float* Ib = I + (size_t)b * L_ * D_;
    const float* Jb = Jm + (size_t)b * L_ * D_;

    __shared__ float As[16][65];
    __shared__ float Bs[16][65];
    __shared__ float cmx[64], csm[64];
    const int tx = threadIdx.x, ty = threadIdx.y;
    const int tid = ty * 16 + tx;
    if (tid < 64) {
        cmx[tid] = cmax[b * L_ + j0 + tid];
        csm[tid] = 1.0f / csum[b * L_ + j0 + tid];
    }
    __syncthreads();

    float acc[4][4] = {};
    for (int k0 = 0; k0 < L_; k0 += 16) {
#pragma unroll
        for (int m = 0; m < 4; ++m) {
            int e = m * 256 + tid;
            int kk = e >> 6, c = e & 63;  // c: jj for A, dd for B (both coalesced)
            As[kk][c] = __expf(Sb[(size_t)(k0 + kk) * L_ + j0 + c] - cmx[c]);
            Bs[kk][c] = Ib[(size_t)(k0 + kk) * D_ + d0 + c];
        }
        __syncthreads();
#pragma unroll
        for (int k = 0; k < 16; ++k) {
            float a[4], bv[4];
#pragma unroll
            for (int m = 0; m < 4; ++m) a[m] = As[k][ty + m * 16];
#pragma unroll
            for (int n = 0; n < 4; ++n) bv[n] = Bs[k][tx + n * 16];
#pragma unroll
            for (int m = 0; m < 4; ++m)
#pragma unroll
                for (int n = 0; n < 4; ++n) acc[m][n] = fmaf(a[m], bv[n], acc[m][n]);
        }
        __syncthreads();
    }
#pragma unroll
    for (int m = 0; m < 4; ++m) {
        int j = j0 + ty + m * 16;
        float inv = csm[ty + m * 16];
#pragma unroll
        for (int n = 0; n < 4; ++n) {
            int d = d0 + tx + n * 16;
            float wv = acc[m][n] * inv;
            Xj[(size_t)b * L_ * D_ + (size_t)j * D_ + d] = fabsf(Jb[(size_t)j * D_ + d] - wv);
        }
    }
}

__global__ __launch_bounds__(256) void zero_out_kernel(float* __restrict__ out) {
    out[blockIdx.x * 256 + threadIdx.x] = 0.0f;
}

// out[b,h] += (0.5/L) * sum_l tanh( sum_d X[b,l,d]*W[d,h] + bias[h] ), X = Xi or Xj
__global__ __launch_bounds__(256) void agg_kernel(const float* __restrict__ Xi,
                                                  const float* __restrict__ Xj,
                                                  const float* __restrict__ W,
                                                  const float* __restrict__ bias,
                                                  float* __restrict__ out) {
    const int bz = blockIdx.z;
    const int b = bz >> 1;
    const float* Xb = ((bz & 1) ? Xj : Xi) + (size_t)b * L_ * D_;
    const int l0 = blockIdx.y * 64;
    const int h0 = blockIdx.x * 64;

    __shared__ float As[16][65];
    __shared__ float Bs[16][65];
    __shared__ float colsum[64];
    const int tx = threadIdx.x, ty = threadIdx.y;
    const int tid = ty * 16 + tx;
    if (tid < 64) colsum[tid] = 0.0f;

    float acc[4][4] = {};
    for (int k0 = 0; k0 < D_; k0 += 16) {
#pragma unroll
        for (int m = 0; m < 4; ++m) {
            int e = m * 256 + tid;
            {
                int ii = e >> 4, kk = e & 15;
                As[kk][ii] = Xb[(size_t)(l0 + ii) * D_ + k0 + kk];
            }
            {
                int kk = e >> 6, dd = e & 63;
                Bs[kk][dd] = W[(size_t)(k0 + kk) * H_ + h0 + dd];
            }
        }
        __syncthreads();
#pragma unroll
        for (int k = 0; k < 16; ++k) {
            float a[4], bv[4];
#pragma unroll
            for (int m = 0; m < 4; ++m) a[m] = As[k][ty + m * 16];
#pragma unroll
            for (int n = 0; n < 4; ++n) bv[n] = Bs[k][tx + n * 16];
#pragma unroll
            for (int m = 0; m < 4; ++m)
#pragma unroll
                for (int n = 0; n < 4; ++n) acc[m][n] = fmaf(a[m], bv[n], acc[m][n]);
        }
        __syncthreads();
    }

#pragma unroll
    for (int n = 0; n < 4; ++n) {
        float bb = bias[h0 + tx + n * 16];
        float s = 0.f;
#pragma unroll
        for (int m = 0; m < 4; ++m) s += tanhf(acc[m][n] + bb);
        atomicAdd(&colsum[tx + n * 16], s);
    }
    __syncthreads();
    if (tid < 64) atomicAdd(&out[b * H_ + h0 + tid], colsum[tid] * (0.5f / (float)L_));
}

extern "C" void kernel_launch(void* const* d_in, const int* in_sizes, int n_in,
                              void* d_out, int out_size, void* d_ws, size_t ws_size,
                              hipStream_t stream) {
    const float* I = (const float*)d_in[0];     // [B, L, D]
    const float* Jm = (const float*)d_in[1];    // [B, L, D]
    const float* W = (const float*)d_in[2];     // [D, H]
    const float* bias = (const float*)d_in[3];  // [H]
    float* out = (float*)d_out;                 // [B, H]

    float* ws = (float*)d_ws;
    float* S = ws;                                  // B*L*L
    float* Xi = S + (size_t)B_ * L_ * L_;           // B*L*D
    float* Xj = Xi + (size_t)B_ * L_ * D_;          // B*L*D
    float* rmax = Xj + (size_t)B_ * L_ * D_;        // B*L
    float* rsum = rmax + B_ * L_;
    float* cmax = rsum + B_ * L_;
    float* csum = cmax + B_ * L_;

    const dim3 blk(16, 16);
    score_kernel<<<dim3(8, 8, B_), blk, 0, stream>>>(I, Jm, S);
    row_stats_kernel<<<dim3(B_ * L_), 256, 0, stream>>>(S, rmax, rsum);
    col_stats_kernel<<<dim3(16, 1, B_), dim3(32, 8), 0, stream>>>(S, cmax, csum);
    wj_kernel<<<dim3(8, 8, B_), blk, 0, stream>>>(S, Jm, I, rmax, rsum, Xi);
    wi_kernel<<<dim3(8, 8, B_), blk, 0, stream>>>(S, I, Jm, cmax, csum, Xj);
    zero_out_kernel<<<dim3((B_ * H_) / 256), 256, 0, stream>>>(out);
    agg_kernel<<<dim3(8, 8, 2 * B_), blk, 0, stream>>>(Xi, Xj, W, bias, out);
}

// Round 2
// 313.937 us; speedup vs baseline: 2.9211x; 2.9211x over previous
//
#include <hip/hip_runtime.h>
#include <math.h>

#define B_ 32
#define L_ 512
#define D_ 512
#define H_ 512

typedef unsigned short u16;
typedef short bf16x8 __attribute__((ext_vector_type(8)));
typedef float f32x4 __attribute__((ext_vector_type(4)));

// chunk swizzle: 16B chunks within a 64B LDS row, XOR by (row>>1)&3.
// Frag reads (ds_read_b128, 16 rows x 16B) land as 2-way bank aliasing = free.
#define SW(r, c) ((c) ^ (((r) >> 1) & 3))

// async global->LDS, 16B per lane; LDS dest = base + lane*16 (wave-uniform base)
typedef __attribute__((address_space(1))) void gvoid;
typedef __attribute__((address_space(3))) void svoid;
__device__ __forceinline__ void async_cp16(const void* g, void* l) {
    __builtin_amdgcn_global_load_lds((gvoid*)g, (svoid*)l, 16, 0, 0);
}

__device__ __forceinline__ unsigned f2bf(float x) {
    unsigned u = __float_as_uint(x);
    u += 0x7FFF + ((u >> 16) & 1);  // RNE
    return u >> 16;
}

// ---------------------------------------------------------------------------
// fp32 -> bf16 hi (+ optional lo residual) split
// ---------------------------------------------------------------------------
__global__ __launch_bounds__(256) void cvt_split(const float* __restrict__ src,
                                                 u16* __restrict__ hi,
                                                 u16* __restrict__ lo, int n4) {
    int t = blockIdx.x * 256 + threadIdx.x;
    if (t >= n4) return;
    f32x4 v = ((const f32x4*)src)[t];
    unsigned h0 = f2bf(v[0]), h1 = f2bf(v[1]), h2 = f2bf(v[2]), h3 = f2bf(v[3]);
    *(uint2*)(hi + (size_t)t * 4) = make_uint2(h0 | (h1 << 16), h2 | (h3 << 16));
    if (lo) {
        unsigned l0 = f2bf(v[0] - __uint_as_float(h0 << 16));
        unsigned l1 = f2bf(v[1] - __uint_as_float(h1 << 16));
        unsigned l2 = f2bf(v[2] - __uint_as_float(h2 << 16));
        unsigned l3 = f2bf(v[3] - __uint_as_float(h3 << 16));
        *(uint2*)(lo + (size_t)t * 4) = make_uint2(l0 | (l1 << 16), l2 | (l3 << 16));
    }
}

// 512x512 u16 transpose per blockIdx.z batch, 64x64 tiles
__global__ __launch_bounds__(256) void transpose_u16(const u16* __restrict__ src,
                                                     u16* __restrict__ dst) {
    const size_t base = (size_t)blockIdx.z * 512 * 512;
    const int r0 = blockIdx.y * 64, c0 = blockIdx.x * 64;
    __shared__ u16 t[64][66];
    const int tid = threadIdx.x;
    const int tr = tid >> 4, tc4 = (tid & 15) * 4;
#pragma unroll
    for (int rep = 0; rep < 4; ++rep) {
        int r = rep * 16 + tr;
        uint2 v = *(const uint2*)(src + base + (size_t)(r0 + r) * 512 + c0 + tc4);
        *(unsigned*)&t[r][tc4] = v.x;
        *(unsigned*)&t[r][tc4 + 2] = v.y;
    }
    __syncthreads();
#pragma unroll
    for (int rep = 0; rep < 4; ++rep) {
        int r = rep * 16 + tr;
        unsigned a = t[tc4][r], b = t[tc4 + 1][r], c = t[tc4 + 2][r], d = t[tc4 + 3][r];
        *(uint2*)(dst + base + (size_t)(c0 + r) * 512 + r0 + tc4) =
            make_uint2(a | (b << 16), c | (d << 16));
    }
}

// ---------------------------------------------------------------------------
// score: S = I.J^T via split-bf16 (hi*hi + hi*lo + lo*hi), fp32 out; also S^T
// ---------------------------------------------------------------------------
__global__ __launch_bounds__(256, 2) void score_mfma(const u16* __restrict__ Ihi,
                                                     const u16* __restrict__ Ilo,
                                                     const u16* __restrict__ Jhi,
                                                     const u16* __restrict__ Jlo,
                                                     float* __restrict__ S,
                                                     float* __restrict__ St) {
    const int b = blockIdx.z, i0 = blockIdx.y * 128, j0 = blockIdx.x * 128;
    __shared__ u16 Ah[128 * 32], Al[128 * 32], Bh[128 * 32], Bl[128 * 32];
    const int tid = threadIdx.x;
    const int wave = tid >> 6, lane = tid & 63;
    const int wm = (wave >> 1) * 64, wn = (wave & 1) * 64;
    const int lr = lane & 15, q = lane >> 4;
    const size_t boff = (size_t)b * L_ * D_;
    const u16* Ibh = Ihi + boff; const u16* Ibl = Ilo + boff;
    const u16* Jbh = Jhi + boff; const u16* Jbl = Jlo + boff;

    f32x4 acc[4][4] = {};

    for (int k0 = 0; k0 < D_; k0 += 32) {
#pragma unroll
        for (int h = 0; h < 2; ++h) {
            int g = wave * 2 + h;
            int r = g * 16 + (lane >> 2);
            int cg = SW(r, lane & 3);
            size_t goi = (size_t)(i0 + r) * D_ + k0 + cg * 8;
            size_t goj = (size_t)(j0 + r) * D_ + k0 + cg * 8;
            int lb = g * 1024;
            async_cp16(Ibh + goi, (char*)Ah + lb);
            async_cp16(Ibl + goi, (char*)Al + lb);
            async_cp16(Jbh + goj, (char*)Bh + lb);
            async_cp16(Jbl + goj, (char*)Bl + lb);
        }
        __syncthreads();
        bf16x8 ah[4], al[4], bh[4], bl[4];
#pragma unroll
        for (int mi = 0; mi < 4; ++mi) {
            int r = wm + mi * 16 + lr;
            int off = r * 32 + SW(r, q) * 8;
            ah[mi] = *(const bf16x8*)&Ah[off];
            al[mi] = *(const bf16x8*)&Al[off];
        }
#pragma unroll
        for (int ni = 0; ni < 4; ++ni) {
            int r = wn + ni * 16 + lr;
            int off = r * 32 + SW(r, q) * 8;
            bh[ni] = *(const bf16x8*)&Bh[off];
            bl[ni] = *(const bf16x8*)&Bl[off];
        }
#pragma unroll
        for (int mi = 0; mi < 4; ++mi)
#pragma unroll
            for (int ni = 0; ni < 4; ++ni) {
                acc[mi][ni] = __builtin_amdgcn_mfma_f32_16x16x32_bf16(ah[mi], bh[ni], acc[mi][ni], 0, 0, 0);
                acc[mi][ni] = __builtin_amdgcn_mfma_f32_16x16x32_bf16(ah[mi], bl[ni], acc[mi][ni], 0, 0, 0);
                acc[mi][ni] = __builtin_amdgcn_mfma_f32_16x16x32_bf16(al[mi], bh[ni], acc[mi][ni], 0, 0, 0);
            }
        __syncthreads();
    }

    float* Sb = S + (size_t)b * L_ * L_;
    float* Stb = St + (size_t)b * L_ * L_;
#pragma unroll
    for (int mi = 0; mi < 4; ++mi)
#pragma unroll
        for (int ni = 0; ni < 4; ++ni) {
            int i = i0 + wm + mi * 16 + q * 4;
            int j = j0 + wn + ni * 16 + lr;
#pragma unroll
            for (int r4 = 0; r4 < 4; ++r4)
                Sb[(size_t)(i + r4) * L_ + j] = acc[mi][ni][r4];
            *(f32x4*)&Stb[(size_t)j * L_ + i] = acc[mi][ni];  // S^T, contiguous 16B
        }
}

// per-row max + sum(exp(x-max)) over 512 entries (used for S rows and S^T rows)
__global__ __launch_bounds__(256) void row_stats_kernel(const float* __restrict__ S,
                                                        float* __restrict__ rmax,
                                                        float* __restrict__ rsum) {
    const int row = blockIdx.x;
    const float* Sr = S + (size_t)row * L_;
    const int t = threadIdx.x;
    float v1 = Sr[t], v2 = Sr[t + 256];
    __shared__ float red[256];
    red[t] = fmaxf(v1, v2);
    __syncthreads();
    for (int s = 128; s > 0; s >>= 1) {
        if (t < s) red[t] = fmaxf(red[t], red[t + s]);
        __syncthreads();
    }
    const float mx = red[0];
    __syncthreads();
    red[t] = __expf(v1 - mx) + __expf(v2 - mx);
    __syncthreads();
    for (int s = 128; s > 0; s >>= 1) {
        if (t < s) red[t] += red[t + s];
        __syncthreads();
    }
    if (t == 0) {
        rmax[row] = mx;
        rsum[row] = red[0];
    }
}

// ---------------------------------------------------------------------------
// X = | O - softmax(Srow) . V |  in bf16.
// A-tile: bf16(exp(S[row][k]-rmax)) staged via VALU; B-tile: Vt[d][k] async.
// Used for both sides: (S, Jhi^T, I) and (S^T, Ihi^T, J).
// ---------------------------------------------------------------------------
__global__ __launch_bounds__(256, 2) void wj_mfma(const float* __restrict__ S,
                                                  const u16* __restrict__ Vt,
                                                  const float* __restrict__ Orig,
                                                  const float* __restrict__ rmax,
                                                  const float* __restrict__ rsum,
                                                  u16* __restrict__ Xout) {
    const int b = blockIdx.z, i0 = blockIdx.y * 128, d0 = blockIdx.x * 128;
    __shared__ u16 At[128 * 32], Bs[128 * 32];
    __shared__ float rmx[128], rsm[128];
    const int tid = threadIdx.x;
    const int wave = tid >> 6, lane = tid & 63;
    const int wm = (wave >> 1) * 64, wn = (wave & 1) * 64;
    const int lr = lane & 15, q = lane >> 4;
    const float* Sb = S + (size_t)b * L_ * L_;
    const u16* Vtb = Vt + (size_t)b * D_ * L_;

    if (tid < 128) {
        rmx[tid] = rmax[b * L_ + i0 + tid];
        rsm[tid] = 1.0f / rsum[b * L_ + i0 + tid];
    }
    __syncthreads();

    f32x4 acc[4][4] = {};

    for (int k0 = 0; k0 < L_; k0 += 32) {
#pragma unroll
        for (int h = 0; h < 2; ++h) {  // B: async from Vt rows (n = d)
            int g = wave * 2 + h;
            int r = g * 16 + (lane >> 2);
            int cg = SW(r, lane & 3);
            async_cp16(Vtb + (size_t)(d0 + r) * L_ + k0 + cg * 8, (char*)Bs + g * 1024);
        }
#pragma unroll
        for (int h = 0; h < 2; ++h) {  // A: exp(S - rmax) -> bf16, swizzled
            int ch = h * 256 + tid;
            int r = ch >> 2, cs = ch & 3;
            int cg = SW(r, cs);
            const float* sp = Sb + (size_t)(i0 + r) * L_ + k0 + cg * 8;
            f32x4 v0 = *(const f32x4*)sp;
            f32x4 v1 = *(const f32x4*)(sp + 4);
            float m = rmx[r];
            bf16x8 pk;
            pk[0] = (short)f2bf(__expf(v0[0] - m));
            pk[1] = (short)f2bf(__expf(v0[1] - m));
            pk[2] = (short)f2bf(__expf(v0[2] - m));
            pk[3] = (short)f2bf(__expf(v0[3] - m));
            pk[4] = (short)f2bf(__expf(v1[0] - m));
            pk[5] = (short)f2bf(__expf(v1[1] - m));
            pk[6] = (short)f2bf(__expf(v1[2] - m));
            pk[7] = (short)f2bf(__expf(v1[3] - m));
            *(bf16x8*)((char*)At + ch * 16) = pk;
        }
        __syncthreads();
        bf16x8 af[4], bf[4];
#pragma unroll
        for (int mi = 0; mi < 4; ++mi) {
            int r = wm + mi * 16 + lr;
            af[mi] = *(const bf16x8*)&At[r * 32 + SW(r, q) * 8];
        }
#pragma unroll
        for (int ni = 0; ni < 4; ++ni) {
            int r = wn + ni * 16 + lr;
            bf[ni] = *(const bf16x8*)&Bs[r * 32 + SW(r, q) * 8];
        }
#pragma unroll
        for (int mi = 0; mi < 4; ++mi)
#pragma unroll
            for (int ni = 0; ni < 4; ++ni)
                acc[mi][ni] = __builtin_amdgcn_mfma_f32_16x16x32_bf16(af[mi], bf[ni], acc[mi][ni], 0, 0, 0);
        __syncthreads();
    }

    const float* Ob = Orig + (size_t)b * L_ * D_;
    u16* Xb = Xout + (size_t)b * L_ * D_;
#pragma unroll
    for (int mi = 0; mi < 4; ++mi)
#pragma unroll
        for (int ni = 0; ni < 4; ++ni) {
            int i = i0 + wm + mi * 16 + q * 4;
            int d = d0 + wn + ni * 16 + lr;
#pragma unroll
            for (int r4 = 0; r4 < 4; ++r4) {
                float wv = acc[mi][ni][r4] * rsm[wm + mi * 16 + q * 4 + r4];
                float x = fabsf(Ob[(size_t)(i + r4) * D_ + d] - wv);
                Xb[(size_t)(i + r4) * D_ + d] = (u16)f2bf(x);
            }
        }
}

__global__ __launch_bounds__(256) void zero_out_kernel(float* __restrict__ out) {
    out[blockIdx.x * 256 + threadIdx.x] = 0.0f;
}

// ---------------------------------------------------------------------------
// agg: out[b,h] += (0.5/L) * sum_l tanh( X[l,:].W[:,h] + bias[h] )
// A = Xall (bf16 [64][L][D]), B = W^T (bf16 [H][D])
// ---------------------------------------------------------------------------
__global__ __launch_bounds__(256, 2) void agg_mfma(const u16* __restrict__ Xall,
                                                   const u16* __restrict__ Wt,
                                                   const float* __restrict__ bias,
                                                   float* __restrict__ out) {
    const int z = blockIdx.z;  // 0..63: [0,32) side-i batches, [32,64) side-j
    const int bb = z & 31;
    const u16* Xb = Xall + (size_t)z * L_ * D_;
    const int l0 = blockIdx.y * 128, h0 = blockIdx.x * 128;
    __shared__ u16 As[128 * 32], Bs[128 * 32];
    const int tid = threadIdx.x;
    const int wave = tid >> 6, lane = tid & 63;
    const int wm = (wave >> 1) * 64, wn = (wave & 1) * 64;
    const int lr = lane & 15, q = lane >> 4;

    f32x4 acc[4][4] = {};

    for (int k0 = 0; k0 < D_; k0 += 32) {
#pragma unroll
        for (int h = 0; h < 2; ++h) {
            int g = wave * 2 + h;
            int r = g * 16 + (lane >> 2);
            int cg = SW(r, lane & 3);
            async_cp16(Xb + (size_t)(l0 + r) * D_ + k0 + cg * 8, (char*)As + g * 1024);
            async_cp16(Wt + (size_t)(h0 + r) * D_ + k0 + cg * 8, (char*)Bs + g * 1024);
        }
        __syncthreads();
        bf16x8 af[4], bf[4];
#pragma unroll
        for (int mi = 0; mi < 4; ++mi) {
            int r = wm + mi * 16 + lr;
            af[mi] = *(const bf16x8*)&As[r * 32 + SW(r, q) * 8];
        }
#pragma unroll
        for (int ni = 0; ni < 4; ++ni) {
            int r = wn + ni * 16 + lr;
            bf[ni] = *(const bf16x8*)&Bs[r * 32 + SW(r, q) * 8];
        }
#pragma unroll
        for (int mi = 0; mi < 4; ++mi)
#pragma unroll
            for (int ni = 0; ni < 4; ++ni)
                acc[mi][ni] = __builtin_amdgcn_mfma_f32_16x16x32_bf16(af[mi], bf[ni], acc[mi][ni], 0, 0, 0);
        __syncthreads();
    }

#pragma unroll
    for (int ni = 0; ni < 4; ++ni) {
        int hcol = h0 + wn + ni * 16 + lr;
        float bsv = bias[hcol];
        float ssum = 0.f;
#pragma unroll
        for (int mi = 0; mi < 4; ++mi)
#pragma unroll
            for (int r4 = 0; r4 < 4; ++r4)
                ssum += tanhf(acc[mi][ni][r4] + bsv);
        ssum += __shfl_xor(ssum, 16);
        ssum += __shfl_xor(ssum, 32);
        if (q == 0) atomicAdd(&out[bb * H_ + hcol], ssum * (0.5f / (float)L_));
    }
}

extern "C" void kernel_launch(void* const* d_in, const int* in_sizes, int n_in,
                              void* d_out, int out_size, void* d_ws, size_t ws_size,
                              hipStream_t stream) {
    const float* I = (const float*)d_in[0];
    const float* Jm = (const float*)d_in[1];
    const float* W = (const float*)d_in[2];
    const float* bias = (const float*)d_in[3];
    float* out = (float*)d_out;

    const size_t BLD = (size_t)B_ * L_ * D_;  // 8388608
    const size_t BLL = (size_t)B_ * L_ * L_;

    char* p = (char*)d_ws;
    auto give = [&](size_t bytes) {
        char* r = p;
        p += (bytes + 255) & ~(size_t)255;
        return r;
    };
    u16* Ihi = (u16*)give(BLD * 2);
    u16* Jhi = (u16*)give(BLD * 2);
    u16* IhiT = (u16*)give(BLD * 2);
    u16* JhiT = (u16*)give(BLD * 2);
    u16* Whi = (u16*)give((size_t)D_ * H_ * 2);
    u16* WhiT = (u16*)give((size_t)D_ * H_ * 2);
    float* S = (float*)give(BLL * 4);
    float* St = (float*)give(BLL * 4);
    u16* lo_blk = (u16*)give(2 * BLD * 2);  // Ilo+Jlo during score; Xall after
    u16* Ilo = lo_blk;
    u16* Jlo = lo_blk + BLD;
    u16* Xall = lo_blk;
    float* rmax = (float*)give(B_ * L_ * 4);
    float* rsum = (float*)give(B_ * L_ * 4);
    float* cmax = (float*)give(B_ * L_ * 4);
    float* csum = (float*)give(B_ * L_ * 4);

    cvt_split<<<8192, 256, 0, stream>>>(I, Ihi, Ilo, (int)(BLD / 4));
    cvt_split<<<8192, 256, 0, stream>>>(Jm, Jhi, Jlo, (int)(BLD / 4));
    cvt_split<<<256, 256, 0, stream>>>(W, Whi, nullptr, D_ * H_ / 4);
    transpose_u16<<<dim3(8, 8, B_), 256, 0, stream>>>(Ihi, IhiT);
    transpose_u16<<<dim3(8, 8, B_), 256, 0, stream>>>(Jhi, JhiT);
    transpose_u16<<<dim3(8, 8, 1), 256, 0, stream>>>(Whi, WhiT);

    score_mfma<<<dim3(4, 4, B_), 256, 0, stream>>>(Ihi, Ilo, Jhi, Jlo, S, St);
    row_stats_kernel<<<B_ * L_, 256, 0, stream>>>(S, rmax, rsum);
    row_stats_kernel<<<B_ * L_, 256, 0, stream>>>(St, cmax, csum);

    wj_mfma<<<dim3(4, 4, B_), 256, 0, stream>>>(S, JhiT, I, rmax, rsum, Xall);
    wj_mfma<<<dim3(4, 4, B_), 256, 0, stream>>>(St, IhiT, Jm, cmax, csum, Xall + BLD);

    zero_out_kernel<<<64, 256, 0, stream>>>(out);
    agg_mfma<<<dim3(4, 4, 2 * B_), 256, 0, stream>>>(Xall, WhiT, bias, out);
}

// Round 3
// 289.994 us; speedup vs baseline: 3.1623x; 1.0826x over previous
//
#include <hip/hip_runtime.h>
#include <math.h>

#define B_ 32
#define L_ 512
#define D_ 512
#define H_ 512

typedef unsigned short u16;
typedef short bf16x8 __attribute__((ext_vector_type(8)));
typedef float f32x4 __attribute__((ext_vector_type(4)));

// chunk swizzle: 16B chunks within a 64B LDS row, XOR by (row>>1)&3.
#define SW(r, c) ((c) ^ (((r) >> 1) & 3))

typedef __attribute__((address_space(1))) void gvoid;
typedef __attribute__((address_space(3))) void svoid;
__device__ __forceinline__ void async_cp16(const void* g, void* l) {
    __builtin_amdgcn_global_load_lds((gvoid*)g, (svoid*)l, 16, 0, 0);
}

__device__ __forceinline__ unsigned f2bf(float x) {
    unsigned u = __float_as_uint(x);
    u += 0x7FFF + ((u >> 16) & 1);  // RNE
    return u >> 16;
}

// ---------------------------------------------------------------------------
// fused fp32 -> bf16 split + transpose: writes hi (opt), lo (opt), hiT (opt)
// 64x64 tiles per batch slice; src is [z][512][512] fp32
// ---------------------------------------------------------------------------
__global__ __launch_bounds__(256) void cvt_split_T(const float* __restrict__ src,
                                                   u16* __restrict__ hi,
                                                   u16* __restrict__ lo,
                                                   u16* __restrict__ hiT) {
    const size_t base = (size_t)blockIdx.z * 512 * 512;
    const int r0 = blockIdx.y * 64, c0 = blockIdx.x * 64;
    __shared__ u16 t[64][66];
    const int tid = threadIdx.x;
    const int tr = tid >> 4, tc4 = (tid & 15) * 4;
#pragma unroll
    for (int rep = 0; rep < 4; ++rep) {
        int r = rep * 16 + tr;
        f32x4 v = *(const f32x4*)(src + base + (size_t)(r0 + r) * 512 + c0 + tc4);
        unsigned h0 = f2bf(v[0]), h1 = f2bf(v[1]), h2 = f2bf(v[2]), h3 = f2bf(v[3]);
        if (hi)
            *(uint2*)(hi + base + (size_t)(r0 + r) * 512 + c0 + tc4) =
                make_uint2(h0 | (h1 << 16), h2 | (h3 << 16));
        if (lo) {
            unsigned l0 = f2bf(v[0] - __uint_as_float(h0 << 16));
            unsigned l1 = f2bf(v[1] - __uint_as_float(h1 << 16));
            unsigned l2 = f2bf(v[2] - __uint_as_float(h2 << 16));
            unsigned l3 = f2bf(v[3] - __uint_as_float(h3 << 16));
            *(uint2*)(lo + base + (size_t)(r0 + r) * 512 + c0 + tc4) =
                make_uint2(l0 | (l1 << 16), l2 | (l3 << 16));
        }
        t[r][tc4] = (u16)h0; t[r][tc4 + 1] = (u16)h1;
        t[r][tc4 + 2] = (u16)h2; t[r][tc4 + 3] = (u16)h3;
    }
    if (!hiT) return;
    __syncthreads();
#pragma unroll
    for (int rep = 0; rep < 4; ++rep) {
        int r = rep * 16 + tr;
        unsigned a = t[tc4][r], b = t[tc4 + 1][r], c = t[tc4 + 2][r], d = t[tc4 + 3][r];
        *(uint2*)(hiT + base + (size_t)(c0 + r) * 512 + r0 + tc4) =
            make_uint2(a | (b << 16), c | (d << 16));
    }
}

// ---------------------------------------------------------------------------
// score: S = I.J^T via split-bf16 (hi*hi + hi*lo + lo*hi), fp32 out; also S^T
// ---------------------------------------------------------------------------
__global__ __launch_bounds__(256, 2) void score_mfma(const u16* __restrict__ Ihi,
                                                     const u16* __restrict__ Ilo,
                                                     const u16* __restrict__ Jhi,
                                                     const u16* __restrict__ Jlo,
                                                     float* __restrict__ S,
                                                     float* __restrict__ St) {
    const int b = blockIdx.z, i0 = blockIdx.y * 128, j0 = blockIdx.x * 128;
    __shared__ u16 Ah[128 * 32], Al[128 * 32], Bh[128 * 32], Bl[128 * 32];
    const int tid = threadIdx.x;
    const int wave = tid >> 6, lane = tid & 63;
    const int wm = (wave >> 1) * 64, wn = (wave & 1) * 64;
    const int lr = lane & 15, q = lane >> 4;
    const size_t boff = (size_t)b * L_ * D_;
    const u16* Ibh = Ihi + boff; const u16* Ibl = Ilo + boff;
    const u16* Jbh = Jhi + boff; const u16* Jbl = Jlo + boff;

    f32x4 acc[4][4] = {};

    for (int k0 = 0; k0 < D_; k0 += 32) {
#pragma unroll
        for (int h = 0; h < 2; ++h) {
            int g = wave * 2 + h;
            int r = g * 16 + (lane >> 2);
            int cg = SW(r, lane & 3);
            size_t goi = (size_t)(i0 + r) * D_ + k0 + cg * 8;
            size_t goj = (size_t)(j0 + r) * D_ + k0 + cg * 8;
            int lb = g * 1024;
            async_cp16(Ibh + goi, (char*)Ah + lb);
            async_cp16(Ibl + goi, (char*)Al + lb);
            async_cp16(Jbh + goj, (char*)Bh + lb);
            async_cp16(Jbl + goj, (char*)Bl + lb);
        }
        __syncthreads();
        bf16x8 ah[4], al[4], bh[4], bl[4];
#pragma unroll
        for (int mi = 0; mi < 4; ++mi) {
            int r = wm + mi * 16 + lr;
            int off = r * 32 + SW(r, q) * 8;
            ah[mi] = *(const bf16x8*)&Ah[off];
            al[mi] = *(const bf16x8*)&Al[off];
        }
#pragma unroll
        for (int ni = 0; ni < 4; ++ni) {
            int r = wn + ni * 16 + lr;
            int off = r * 32 + SW(r, q) * 8;
            bh[ni] = *(const bf16x8*)&Bh[off];
            bl[ni] = *(const bf16x8*)&Bl[off];
        }
#pragma unroll
        for (int mi = 0; mi < 4; ++mi)
#pragma unroll
            for (int ni = 0; ni < 4; ++ni) {
                acc[mi][ni] = __builtin_amdgcn_mfma_f32_16x16x32_bf16(ah[mi], bh[ni], acc[mi][ni], 0, 0, 0);
                acc[mi][ni] = __builtin_amdgcn_mfma_f32_16x16x32_bf16(ah[mi], bl[ni], acc[mi][ni], 0, 0, 0);
                acc[mi][ni] = __builtin_amdgcn_mfma_f32_16x16x32_bf16(al[mi], bh[ni], acc[mi][ni], 0, 0, 0);
            }
        __syncthreads();
    }

    float* Sb = S + (size_t)b * L_ * L_;
    float* Stb = St + (size_t)b * L_ * L_;
#pragma unroll
    for (int mi = 0; mi < 4; ++mi)
#pragma unroll
        for (int ni = 0; ni < 4; ++ni) {
            int i = i0 + wm + mi * 16 + q * 4;
            int j = j0 + wn + ni * 16 + lr;
#pragma unroll
            for (int r4 = 0; r4 < 4; ++r4)
                Sb[(size_t)(i + r4) * L_ + j] = acc[mi][ni][r4];
            *(f32x4*)&Stb[(size_t)j * L_ + i] = acc[mi][ni];  // S^T, contiguous 16B
        }
}

// ---------------------------------------------------------------------------
// fused row softmax: P[row] = bf16( exp(S[row]-max) / sum ) — one block/row.
// Covers S rows and S^T rows in a single dispatch (contiguous buffers).
// ---------------------------------------------------------------------------
__global__ __launch_bounds__(256) void softmax_rows(const float* __restrict__ S,
                                                    u16* __restrict__ P) {
    const int row = blockIdx.x;
    const float* Sr = S + (size_t)row * L_;
    const int t = threadIdx.x;
    float2 v = *(const float2*)(Sr + 2 * t);
    __shared__ float red[256];
    red[t] = fmaxf(v.x, v.y);
    __syncthreads();
    for (int s = 128; s > 0; s >>= 1) {
        if (t < s) red[t] = fmaxf(red[t], red[t + s]);
        __syncthreads();
    }
    const float mx = red[0];
    __syncthreads();
    float e0 = __expf(v.x - mx), e1 = __expf(v.y - mx);
    red[t] = e0 + e1;
    __syncthreads();
    for (int s = 128; s > 0; s >>= 1) {
        if (t < s) red[t] += red[t + s];
        __syncthreads();
    }
    const float inv = 1.0f / red[0];
    ((unsigned*)(P + (size_t)row * L_))[t] = f2bf(e0 * inv) | (f2bf(e1 * inv) << 16);
}

// ---------------------------------------------------------------------------
// X = | O - P . Vt^T | in bf16. Pure async bf16 GEMM, agg-style loop.
// A = P [L x L] bf16 (k contiguous), B = Vt [D x L] bf16 (k contiguous).
// ---------------------------------------------------------------------------
__global__ __launch_bounds__(256, 2) void absdiff_gemm(const u16* __restrict__ P,
                                                       const u16* __restrict__ Vt,
                                                       const float* __restrict__ Orig,
                                                       u16* __restrict__ Xout) {
    const int b = blockIdx.z, i0 = blockIdx.x * 128, d0 = blockIdx.y * 128;
    __shared__ u16 As[128 * 32], Bs[128 * 32];
    const int tid = threadIdx.x;
    const int wave = tid >> 6, lane = tid & 63;
    const int wm = (wave >> 1) * 64, wn = (wave & 1) * 64;
    const int lr = lane & 15, q = lane >> 4;
    const u16* Pb = P + (size_t)b * L_ * L_;
    const u16* Vtb = Vt + (size_t)b * D_ * L_;

    f32x4 acc[4][4] = {};

    for (int k0 = 0; k0 < L_; k0 += 32) {
#pragma unroll
        for (int h = 0; h < 2; ++h) {
            int g = wave * 2 + h;
            int r = g * 16 + (lane >> 2);
            int cg = SW(r, lane & 3);
            async_cp16(Pb + (size_t)(i0 + r) * L_ + k0 + cg * 8, (char*)As + g * 1024);
            async_cp16(Vtb + (size_t)(d0 + r) * L_ + k0 + cg * 8, (char*)Bs + g * 1024);
        }
        __syncthreads();
        bf16x8 af[4], bf[4];
#pragma unroll
        for (int mi = 0; mi < 4; ++mi) {
            int r = wm + mi * 16 + lr;
            af[mi] = *(const bf16x8*)&As[r * 32 + SW(r, q) * 8];
        }
#pragma unroll
        for (int ni = 0; ni < 4; ++ni) {
            int r = wn + ni * 16 + lr;
            bf[ni] = *(const bf16x8*)&Bs[r * 32 + SW(r, q) * 8];
        }
#pragma unroll
        for (int mi = 0; mi < 4; ++mi)
#pragma unroll
            for (int ni = 0; ni < 4; ++ni)
                acc[mi][ni] = __builtin_amdgcn_mfma_f32_16x16x32_bf16(af[mi], bf[ni], acc[mi][ni], 0, 0, 0);
        __syncthreads();
    }

    const float* Ob = Orig + (size_t)b * L_ * D_;
    u16* Xb = Xout + (size_t)b * L_ * D_;
#pragma unroll
    for (int mi = 0; mi < 4; ++mi)
#pragma unroll
        for (int ni = 0; ni < 4; ++ni) {
            int i = i0 + wm + mi * 16 + q * 4;
            int d = d0 + wn + ni * 16 + lr;
#pragma unroll
            for (int r4 = 0; r4 < 4; ++r4) {
                float x = fabsf(Ob[(size_t)(i + r4) * D_ + d] - acc[mi][ni][r4]);
                Xb[(size_t)(i + r4) * D_ + d] = (u16)f2bf(x);
            }
        }
}

__global__ __launch_bounds__(256) void zero_out_kernel(float* __restrict__ out) {
    out[blockIdx.x * 256 + threadIdx.x] = 0.0f;
}

// ---------------------------------------------------------------------------
// agg: out[b,h] += (0.5/L) * sum_l tanh( X[l,:].W[:,h] + bias[h] )
// grid.x = l-tile so same-XCD block pairs (ids 8 apart) share the X strip.
// ---------------------------------------------------------------------------
__global__ __launch_bounds__(256, 2) void agg_mfma(const u16* __restrict__ Xall,
                                                   const u16* __restrict__ Wt,
                                                   const float* __restrict__ bias,
                                                   float* __restrict__ out) {
    const int z = blockIdx.z;  // 0..63
    const int bb = z & 31;
    const u16* Xb = Xall + (size_t)z * L_ * D_;
    const int l0 = blockIdx.x * 128, h0 = blockIdx.y * 128;
    __shared__ u16 As[128 * 32], Bs[128 * 32];
    const int tid = threadIdx.x;
    const int wave = tid >> 6, lane = tid & 63;
    const int wm = (wave >> 1) * 64, wn = (wave & 1) * 64;
    const int lr = lane & 15, q = lane >> 4;

    f32x4 acc[4][4] = {};

    for (int k0 = 0; k0 < D_; k0 += 32) {
#pragma unroll
        for (int h = 0; h < 2; ++h) {
            int g = wave * 2 + h;
            int r = g * 16 + (lane >> 2);
            int cg = SW(r, lane & 3);
            async_cp16(Xb + (size_t)(l0 + r) * D_ + k0 + cg * 8, (char*)As + g * 1024);
            async_cp16(Wt + (size_t)(h0 + r) * D_ + k0 + cg * 8, (char*)Bs + g * 1024);
        }
        __syncthreads();
        bf16x8 af[4], bf[4];
#pragma unroll
        for (int mi = 0; mi < 4; ++mi) {
            int r = wm + mi * 16 + lr;
            af[mi] = *(const bf16x8*)&As[r * 32 + SW(r, q) * 8];
        }
#pragma unroll
        for (int ni = 0; ni < 4; ++ni) {
            int r = wn + ni * 16 + lr;
            bf[ni] = *(const bf16x8*)&Bs[r * 32 + SW(r, q) * 8];
        }
#pragma unroll
        for (int mi = 0; mi < 4; ++mi)
#pragma unroll
            for (int ni = 0; ni < 4; ++ni)
                acc[mi][ni] = __builtin_amdgcn_mfma_f32_16x16x32_bf16(af[mi], bf[ni], acc[mi][ni], 0, 0, 0);
        __syncthreads();
    }

#pragma unroll
    for (int ni = 0; ni < 4; ++ni) {
        int hcol = h0 + wn + ni * 16 + lr;
        float bsv = bias[hcol];
        float ssum = 0.f;
#pragma unroll
        for (int mi = 0; mi < 4; ++mi)
#pragma unroll
            for (int r4 = 0; r4 < 4; ++r4)
                ssum += tanhf(acc[mi][ni][r4] + bsv);
        ssum += __shfl_xor(ssum, 16);
        ssum += __shfl_xor(ssum, 32);
        if (q == 0) atomicAdd(&out[bb * H_ + hcol], ssum * (0.5f / (float)L_));
    }
}

extern "C" void kernel_launch(void* const* d_in, const int* in_sizes, int n_in,
                              void* d_out, int out_size, void* d_ws, size_t ws_size,
                              hipStream_t stream) {
    const float* I = (const float*)d_in[0];
    const float* Jm = (const float*)d_in[1];
    const float* W = (const float*)d_in[2];
    const float* bias = (const float*)d_in[3];
    float* out = (float*)d_out;

    const size_t BLD = (size_t)B_ * L_ * D_;
    const size_t BLL = (size_t)B_ * L_ * L_;

    char* p = (char*)d_ws;
    auto give = [&](size_t bytes) {
        char* r = p;
        p += (bytes + 255) & ~(size_t)255;
        return r;
    };
    u16* Ihi = (u16*)give(BLD * 2);
    u16* Jhi = (u16*)give(BLD * 2);
    u16* IhiT = (u16*)give(BLD * 2);
    u16* JhiT = (u16*)give(BLD * 2);
    u16* WhiT = (u16*)give((size_t)D_ * H_ * 2);
    float* S = (float*)give(2 * BLL * 4);  // S then St contiguous; Xall aliases later
    float* St = S + BLL;
    u16* lo_blk = (u16*)give(2 * BLD * 2);  // Ilo+Jlo during score; Prow+Pcol after
    u16* Ilo = lo_blk;
    u16* Jlo = lo_blk + BLD;
    u16* Prow = lo_blk;          // aliases Ilo/Jlo (dead after score)
    u16* Pcol = lo_blk + BLL;
    u16* Xall = (u16*)S;         // aliases S/St (dead after softmax)

    cvt_split_T<<<dim3(8, 8, B_), 256, 0, stream>>>(I, Ihi, Ilo, IhiT);
    cvt_split_T<<<dim3(8, 8, B_), 256, 0, stream>>>(Jm, Jhi, Jlo, JhiT);
    cvt_split_T<<<dim3(8, 8, 1), 256, 0, stream>>>(W, nullptr, nullptr, WhiT);

    score_mfma<<<dim3(4, 4, B_), 256, 0, stream>>>(Ihi, Ilo, Jhi, Jlo, S, St);
    softmax_rows<<<2 * B_ * L_, 256, 0, stream>>>(S, Prow);  // covers S and St rows

    absdiff_gemm<<<dim3(4, 4, B_), 256, 0, stream>>>(Prow, JhiT, I, Xall);
    absdiff_gemm<<<dim3(4, 4, B_), 256, 0, stream>>>(Pcol, IhiT, Jm, Xall + BLD);

    zero_out_kernel<<<64, 256, 0, stream>>>(out);
    agg_mfma<<<dim3(4, 4, 2 * B_), 256, 0, stream>>>(Xall, WhiT, bias, out);
}

// Round 4
// 260.019 us; speedup vs baseline: 3.5268x; 1.1153x over previous
//
#include <hip/hip_runtime.h>
#include <math.h>

#define B_ 32
#define L_ 512
#define D_ 512
#define H_ 512

typedef unsigned short u16;
typedef _Float16 h16;
typedef h16 half8 __attribute__((ext_vector_type(8)));
typedef float f32x4 __attribute__((ext_vector_type(4)));

// chunk swizzle: 16B chunks within a 64B LDS row, XOR by (row>>1)&3.
#define SW(r, c) ((c) ^ (((r) >> 1) & 3))

typedef __attribute__((address_space(1))) void gvoid;
typedef __attribute__((address_space(3))) void svoid;
__device__ __forceinline__ void async_cp16(const void* g, void* l) {
    __builtin_amdgcn_global_load_lds((gvoid*)g, (svoid*)l, 16, 0, 0);
}

__device__ __forceinline__ u16 f2h(float x) {
    h16 h = (h16)x;
    u16 r;
    __builtin_memcpy(&r, &h, 2);
    return r;
}
__device__ __forceinline__ float h2f(u16 u) {
    h16 h;
    __builtin_memcpy(&h, &u, 2);
    return (float)h;
}

// ---------------------------------------------------------------------------
// fused fp32 -> fp16 convert + transpose: writes h (opt) and hT (opt)
// 64x64 tiles per batch slice; src is [z][512][512] fp32
// ---------------------------------------------------------------------------
__global__ __launch_bounds__(256) void cvt_h_T(const float* __restrict__ src,
                                               u16* __restrict__ h,
                                               u16* __restrict__ hT) {
    const size_t base = (size_t)blockIdx.z * 512 * 512;
    const int r0 = blockIdx.y * 64, c0 = blockIdx.x * 64;
    __shared__ u16 t[64][66];
    const int tid = threadIdx.x;
    const int tr = tid >> 4, tc4 = (tid & 15) * 4;
#pragma unroll
    for (int rep = 0; rep < 4; ++rep) {
        int r = rep * 16 + tr;
        f32x4 v = *(const f32x4*)(src + base + (size_t)(r0 + r) * 512 + c0 + tc4);
        unsigned h0 = f2h(v[0]), h1 = f2h(v[1]), h2 = f2h(v[2]), h3 = f2h(v[3]);
        if (h)
            *(uint2*)(h + base + (size_t)(r0 + r) * 512 + c0 + tc4) =
                make_uint2(h0 | (h1 << 16), h2 | (h3 << 16));
        t[r][tc4] = (u16)h0; t[r][tc4 + 1] = (u16)h1;
        t[r][tc4 + 2] = (u16)h2; t[r][tc4 + 3] = (u16)h3;
    }
    if (!hT) return;
    __syncthreads();
#pragma unroll
    for (int rep = 0; rep < 4; ++rep) {
        int r = rep * 16 + tr;
        unsigned a = t[tc4][r], b = t[tc4 + 1][r], c = t[tc4 + 2][r], d = t[tc4 + 3][r];
        *(uint2*)(hT + base + (size_t)(c0 + r) * 512 + r0 + tc4) =
            make_uint2(a | (b << 16), c | (d << 16));
    }
}

// ---------------------------------------------------------------------------
// score: S = I.J^T single-fp16 MFMA, fp32 out; also S^T
// ---------------------------------------------------------------------------
__global__ __launch_bounds__(256, 2) void score_mfma(const u16* __restrict__ Ih,
                                                     const u16* __restrict__ Jh,
                                                     float* __restrict__ S,
                                                     float* __restrict__ St) {
    const int b = blockIdx.z, i0 = blockIdx.y * 128, j0 = blockIdx.x * 128;
    __shared__ u16 Ah[128 * 32], Bh[128 * 32];
    const int tid = threadIdx.x;
    const int wave = tid >> 6, lane = tid & 63;
    const int wm = (wave >> 1) * 64, wn = (wave & 1) * 64;
    const int lr = lane & 15, q = lane >> 4;
    const size_t boff = (size_t)b * L_ * D_;
    const u16* Ibh = Ih + boff;
    const u16* Jbh = Jh + boff;

    f32x4 acc[4][4] = {};

    for (int k0 = 0; k0 < D_; k0 += 32) {
#pragma unroll
        for (int h = 0; h < 2; ++h) {
            int g = wave * 2 + h;
            int r = g * 16 + (lane >> 2);
            int cg = SW(r, lane & 3);
            async_cp16(Ibh + (size_t)(i0 + r) * D_ + k0 + cg * 8, (char*)Ah + g * 1024);
            async_cp16(Jbh + (size_t)(j0 + r) * D_ + k0 + cg * 8, (char*)Bh + g * 1024);
        }
        __syncthreads();
        half8 af[4], bf[4];
#pragma unroll
        for (int mi = 0; mi < 4; ++mi) {
            int r = wm + mi * 16 + lr;
            af[mi] = *(const half8*)&Ah[r * 32 + SW(r, q) * 8];
        }
#pragma unroll
        for (int ni = 0; ni < 4; ++ni) {
            int r = wn + ni * 16 + lr;
            bf[ni] = *(const half8*)&Bh[r * 32 + SW(r, q) * 8];
        }
#pragma unroll
        for (int mi = 0; mi < 4; ++mi)
#pragma unroll
            for (int ni = 0; ni < 4; ++ni)
                acc[mi][ni] = __builtin_amdgcn_mfma_f32_16x16x32_f16(af[mi], bf[ni], acc[mi][ni], 0, 0, 0);
        __syncthreads();
    }

    float* Sb = S + (size_t)b * L_ * L_;
    float* Stb = St + (size_t)b * L_ * L_;
#pragma unroll
    for (int mi = 0; mi < 4; ++mi)
#pragma unroll
        for (int ni = 0; ni < 4; ++ni) {
            int i = i0 + wm + mi * 16 + q * 4;
            int j = j0 + wn + ni * 16 + lr;
#pragma unroll
            for (int r4 = 0; r4 < 4; ++r4)
                Sb[(size_t)(i + r4) * L_ + j] = acc[mi][ni][r4];
            *(f32x4*)&Stb[(size_t)j * L_ + i] = acc[mi][ni];  // S^T, contiguous 16B
        }
}

// ---------------------------------------------------------------------------
// fused row softmax: P[row] = fp16( exp(S[row]-max) / sum ) — one block/row.
// Covers S rows and S^T rows in one dispatch (contiguous buffers).
// ---------------------------------------------------------------------------
__global__ __launch_bounds__(256) void softmax_rows(const float* __restrict__ S,
                                                    u16* __restrict__ P) {
    const int row = blockIdx.x;
    const float* Sr = S + (size_t)row * L_;
    const int t = threadIdx.x;
    float2 v = *(const float2*)(Sr + 2 * t);
    __shared__ float red[256];
    red[t] = fmaxf(v.x, v.y);
    __syncthreads();
    for (int s = 128; s > 0; s >>= 1) {
        if (t < s) red[t] = fmaxf(red[t], red[t + s]);
        __syncthreads();
    }
    const float mx = red[0];
    __syncthreads();
    float e0 = __expf(v.x - mx), e1 = __expf(v.y - mx);
    red[t] = e0 + e1;
    __syncthreads();
    for (int s = 128; s > 0; s >>= 1) {
        if (t < s) red[t] += red[t + s];
        __syncthreads();
    }
    const float inv = 1.0f / red[0];
    ((unsigned*)(P + (size_t)row * L_))[t] =
        (unsigned)f2h(e0 * inv) | ((unsigned)f2h(e1 * inv) << 16);
}

// ---------------------------------------------------------------------------
// X = | Oh - P . Vt^T | in fp16. Pure async fp16 GEMM.
// A = P [L x L] fp16 (k contiguous), B = Vt [D x L] fp16 (k contiguous),
// Oh = fp16 original (same matrix the weighted sum is subtracted from).
// ---------------------------------------------------------------------------
__global__ __launch_bounds__(256, 2) void absdiff_gemm(const u16* __restrict__ P,
                                                       const u16* __restrict__ Vt,
                                                       const u16* __restrict__ Oh,
                                                       u16* __restrict__ Xout) {
    const int b = blockIdx.z, i0 = blockIdx.x * 128, d0 = blockIdx.y * 128;
    __shared__ u16 As[128 * 32], Bs[128 * 32];
    const int tid = threadIdx.x;
    const int wave = tid >> 6, lane = tid & 63;
    const int wm = (wave >> 1) * 64, wn = (wave & 1) * 64;
    const int lr = lane & 15, q = lane >> 4;
    const u16* Pb = P + (size_t)b * L_ * L_;
    const u16* Vtb = Vt + (size_t)b * D_ * L_;

    f32x4 acc[4][4] = {};

    for (int k0 = 0; k0 < L_; k0 += 32) {
#pragma unroll
        for (int h = 0; h < 2; ++h) {
            int g = wave * 2 + h;
            int r = g * 16 + (lane >> 2);
            int cg = SW(r, lane & 3);
            async_cp16(Pb + (size_t)(i0 + r) * L_ + k0 + cg * 8, (char*)As + g * 1024);
            async_cp16(Vtb + (size_t)(d0 + r) * L_ + k0 + cg * 8, (char*)Bs + g * 1024);
        }
        __syncthreads();
        half8 af[4], bf[4];
#pragma unroll
        for (int mi = 0; mi < 4; ++mi) {
            int r = wm + mi * 16 + lr;
            af[mi] = *(const half8*)&As[r * 32 + SW(r, q) * 8];
        }
#pragma unroll
        for (int ni = 0; ni < 4; ++ni) {
            int r = wn + ni * 16 + lr;
            bf[ni] = *(const half8*)&Bs[r * 32 + SW(r, q) * 8];
        }
#pragma unroll
        for (int mi = 0; mi < 4; ++mi)
#pragma unroll
            for (int ni = 0; ni < 4; ++ni)
                acc[mi][ni] = __builtin_amdgcn_mfma_f32_16x16x32_f16(af[mi], bf[ni], acc[mi][ni], 0, 0, 0);
        __syncthreads();
    }

    const u16* Ob = Oh + (size_t)b * L_ * D_;
    u16* Xb = Xout + (size_t)b * L_ * D_;
#pragma unroll
    for (int mi = 0; mi < 4; ++mi)
#pragma unroll
        for (int ni = 0; ni < 4; ++ni) {
            int i = i0 + wm + mi * 16 + q * 4;
            int d = d0 + wn + ni * 16 + lr;
#pragma unroll
            for (int r4 = 0; r4 < 4; ++r4) {
                float x = fabsf(h2f(Ob[(size_t)(i + r4) * D_ + d]) - acc[mi][ni][r4]);
                Xb[(size_t)(i + r4) * D_ + d] = f2h(x);
            }
        }
}

__global__ __launch_bounds__(256) void zero_out_kernel(float* __restrict__ out) {
    out[blockIdx.x * 256 + threadIdx.x] = 0.0f;
}

// ---------------------------------------------------------------------------
// agg: out[b,h] += (0.5/L) * sum_l tanh( X[l,:].W[:,h] + bias[h] )
// ---------------------------------------------------------------------------
__global__ __launch_bounds__(256, 2) void agg_mfma(const u16* __restrict__ Xall,
                                                   const u16* __restrict__ Wt,
                                                   const float* __restrict__ bias,
                                                   float* __restrict__ out) {
    const int z = blockIdx.z;  // 0..63
    const int bb = z & 31;
    const u16* Xb = Xall + (size_t)z * L_ * D_;
    const int l0 = blockIdx.x * 128, h0 = blockIdx.y * 128;
    __shared__ u16 As[128 * 32], Bs[128 * 32];
    const int tid = threadIdx.x;
    const int wave = tid >> 6, lane = tid & 63;
    const int wm = (wave >> 1) * 64, wn = (wave & 1) * 64;
    const int lr = lane & 15, q = lane >> 4;

    f32x4 acc[4][4] = {};

    for (int k0 = 0; k0 < D_; k0 += 32) {
#pragma unroll
        for (int h = 0; h < 2; ++h) {
            int g = wave * 2 + h;
            int r = g * 16 + (lane >> 2);
            int cg = SW(r, lane & 3);
            async_cp16(Xb + (size_t)(l0 + r) * D_ + k0 + cg * 8, (char*)As + g * 1024);
            async_cp16(Wt + (size_t)(h0 + r) * D_ + k0 + cg * 8, (char*)Bs + g * 1024);
        }
        __syncthreads();
        half8 af[4], bf[4];
#pragma unroll
        for (int mi = 0; mi < 4; ++mi) {
            int r = wm + mi * 16 + lr;
            af[mi] = *(const half8*)&As[r * 32 + SW(r, q) * 8];
        }
#pragma unroll
        for (int ni = 0; ni < 4; ++ni) {
            int r = wn + ni * 16 + lr;
            bf[ni] = *(const half8*)&Bs[r * 32 + SW(r, q) * 8];
        }
#pragma unroll
        for (int mi = 0; mi < 4; ++mi)
#pragma unroll
            for (int ni = 0; ni < 4; ++ni)
                acc[mi][ni] = __builtin_amdgcn_mfma_f32_16x16x32_f16(af[mi], bf[ni], acc[mi][ni], 0, 0, 0);
        __syncthreads();
    }

#pragma unroll
    for (int ni = 0; ni < 4; ++ni) {
        int hcol = h0 + wn + ni * 16 + lr;
        float bsv = bias[hcol];
        float ssum = 0.f;
#pragma unroll
        for (int mi = 0; mi < 4; ++mi)
#pragma unroll
            for (int r4 = 0; r4 < 4; ++r4)
                ssum += tanhf(acc[mi][ni][r4] + bsv);
        ssum += __shfl_xor(ssum, 16);
        ssum += __shfl_xor(ssum, 32);
        if (q == 0) atomicAdd(&out[bb * H_ + hcol], ssum * (0.5f / (float)L_));
    }
}

extern "C" void kernel_launch(void* const* d_in, const int* in_sizes, int n_in,
                              void* d_out, int out_size, void* d_ws, size_t ws_size,
                              hipStream_t stream) {
    const float* I = (const float*)d_in[0];
    const float* Jm = (const float*)d_in[1];
    const float* W = (const float*)d_in[2];
    const float* bias = (const float*)d_in[3];
    float* out = (float*)d_out;

    const size_t BLD = (size_t)B_ * L_ * D_;
    const size_t BLL = (size_t)B_ * L_ * L_;

    char* p = (char*)d_ws;
    auto give = [&](size_t bytes) {
        char* r = p;
        p += (bytes + 255) & ~(size_t)255;
        return r;
    };
    u16* Ih = (u16*)give(BLD * 2);
    u16* Jh = (u16*)give(BLD * 2);
    u16* IhT = (u16*)give(BLD * 2);
    u16* JhT = (u16*)give(BLD * 2);
    u16* WT = (u16*)give((size_t)D_ * H_ * 2);
    float* S = (float*)give(2 * BLL * 4);  // S then St contiguous; Xall aliases later
    float* St = S + BLL;
    u16* Pblk = (u16*)give(2 * BLL * 2);   // Prow then Pcol
    u16* Prow = Pblk;
    u16* Pcol = Pblk + BLL;
    u16* Xall = (u16*)S;                   // aliases S/St (dead after softmax)

    cvt_h_T<<<dim3(8, 8, B_), 256, 0, stream>>>(I, Ih, IhT);
    cvt_h_T<<<dim3(8, 8, B_), 256, 0, stream>>>(Jm, Jh, JhT);
    cvt_h_T<<<dim3(8, 8, 1), 256, 0, stream>>>(W, nullptr, WT);

    score_mfma<<<dim3(4, 4, B_), 256, 0, stream>>>(Ih, Jh, S, St);
    softmax_rows<<<2 * B_ * L_, 256, 0, stream>>>(S, Prow);  // covers S and St rows

    absdiff_gemm<<<dim3(4, 4, B_), 256, 0, stream>>>(Prow, JhT, Ih, Xall);
    absdiff_gemm<<<dim3(4, 4, B_), 256, 0, stream>>>(Pcol, IhT, Jh, Xall + BLD);

    zero_out_kernel<<<64, 256, 0, stream>>>(out);
    agg_mfma<<<dim3(4, 4, 2 * B_), 256, 0, stream>>>(Xall, WT, bias, out);
}

// Round 5
// 232.779 us; speedup vs baseline: 3.9395x; 1.1170x over previous
//
#include <hip/hip_runtime.h>
#include <math.h>

#define B_ 32
#define L_ 512
#define D_ 512
#define H_ 512

typedef unsigned short u16;
typedef _Float16 h16;
typedef h16 half8 __attribute__((ext_vector_type(8)));
typedef float f32x4 __attribute__((ext_vector_type(4)));

// chunk swizzle: 16B chunks within a 64B LDS row, XOR by (row>>1)&3.
#define SW(r, c) ((c) ^ (((r) >> 1) & 3))

typedef __attribute__((address_space(1))) void gvoid;
typedef __attribute__((address_space(3))) void svoid;
__device__ __forceinline__ void async_cp16(const void* g, void* l) {
    __builtin_amdgcn_global_load_lds((gvoid*)g, (svoid*)l, 16, 0, 0);
}

__device__ __forceinline__ u16 f2h(float x) {
    h16 h = (h16)x;
    u16 r;
    __builtin_memcpy(&r, &h, 2);
    return r;
}
__device__ __forceinline__ float h2f(u16 u) {
    h16 h;
    __builtin_memcpy(&h, &u, 2);
    return (float)h;
}

// ---------------------------------------------------------------------------
// one dispatch: fp32->fp16 convert(+transpose) for I (z<32), J (32<=z<64),
// W (z==64, transposed only). z==64 blocks also zero the output buffer
// (runs first in the graph, so zeroing is complete before agg's atomics).
// ---------------------------------------------------------------------------
__global__ __launch_bounds__(256) void cvt_all(const float* __restrict__ I,
                                               const float* __restrict__ Jm,
                                               const float* __restrict__ W,
                                               u16* __restrict__ Ih, u16* __restrict__ IhT,
                                               u16* __restrict__ Jh, u16* __restrict__ JhT,
                                               u16* __restrict__ WT,
                                               float* __restrict__ out) {
    const int z = blockIdx.z;
    const float* src;
    u16* h;
    u16* hT;
    size_t base;
    if (z < 32) {
        src = I; h = Ih; hT = IhT; base = (size_t)z * 512 * 512;
    } else if (z < 64) {
        src = Jm; h = Jh; hT = JhT; base = (size_t)(z - 32) * 512 * 512;
    } else {
        src = W; h = nullptr; hT = WT; base = 0;
        out[(blockIdx.y * 8 + blockIdx.x) * 256 + threadIdx.x] = 0.0f;
    }
    const int r0 = blockIdx.y * 64, c0 = blockIdx.x * 64;
    __shared__ u16 t[64][66];
    const int tid = threadIdx.x;
    const int tr = tid >> 4, tc4 = (tid & 15) * 4;
#pragma unroll
    for (int rep = 0; rep < 4; ++rep) {
        int r = rep * 16 + tr;
        f32x4 v = *(const f32x4*)(src + base + (size_t)(r0 + r) * 512 + c0 + tc4);
        unsigned h0 = f2h(v[0]), h1 = f2h(v[1]), h2 = f2h(v[2]), h3 = f2h(v[3]);
        if (h)
            *(uint2*)(h + base + (size_t)(r0 + r) * 512 + c0 + tc4) =
                make_uint2(h0 | (h1 << 16), h2 | (h3 << 16));
        t[r][tc4] = (u16)h0; t[r][tc4 + 1] = (u16)h1;
        t[r][tc4 + 2] = (u16)h2; t[r][tc4 + 3] = (u16)h3;
    }
    __syncthreads();
#pragma unroll
    for (int rep = 0; rep < 4; ++rep) {
        int r = rep * 16 + tr;
        unsigned a = t[tc4][r], b = t[tc4 + 1][r], c = t[tc4 + 2][r], d = t[tc4 + 3][r];
        *(uint2*)(hT + base + (size_t)(c0 + r) * 512 + r0 + tc4) =
            make_uint2(a | (b << 16), c | (d << 16));
    }
}

// ---------------------------------------------------------------------------
// score: S = I.J^T single-fp16 MFMA, fp32 out; also S^T
// ---------------------------------------------------------------------------
__global__ __launch_bounds__(256, 2) void score_mfma(const u16* __restrict__ Ih,
                                                     const u16* __restrict__ Jh,
                                                     float* __restrict__ S,
                                                     float* __restrict__ St) {
    const int b = blockIdx.z, i0 = blockIdx.y * 128, j0 = blockIdx.x * 128;
    __shared__ u16 Ah[128 * 32], Bh[128 * 32];
    const int tid = threadIdx.x;
    const int wave = tid >> 6, lane = tid & 63;
    const int wm = (wave >> 1) * 64, wn = (wave & 1) * 64;
    const int lr = lane & 15, q = lane >> 4;
    const size_t boff = (size_t)b * L_ * D_;
    const u16* Ibh = Ih + boff;
    const u16* Jbh = Jh + boff;

    f32x4 acc[4][4] = {};

    for (int k0 = 0; k0 < D_; k0 += 32) {
#pragma unroll
        for (int h = 0; h < 2; ++h) {
            int g = wave * 2 + h;
            int r = g * 16 + (lane >> 2);
            int cg = SW(r, lane & 3);
            async_cp16(Ibh + (size_t)(i0 + r) * D_ + k0 + cg * 8, (char*)Ah + g * 1024);
            async_cp16(Jbh + (size_t)(j0 + r) * D_ + k0 + cg * 8, (char*)Bh + g * 1024);
        }
        __syncthreads();
        half8 af[4], bf[4];
#pragma unroll
        for (int mi = 0; mi < 4; ++mi) {
            int r = wm + mi * 16 + lr;
            af[mi] = *(const half8*)&Ah[r * 32 + SW(r, q) * 8];
        }
#pragma unroll
        for (int ni = 0; ni < 4; ++ni) {
            int r = wn + ni * 16 + lr;
            bf[ni] = *(const half8*)&Bh[r * 32 + SW(r, q) * 8];
        }
#pragma unroll
        for (int mi = 0; mi < 4; ++mi)
#pragma unroll
            for (int ni = 0; ni < 4; ++ni)
                acc[mi][ni] = __builtin_amdgcn_mfma_f32_16x16x32_f16(af[mi], bf[ni], acc[mi][ni], 0, 0, 0);
        __syncthreads();
    }

    float* Sb = S + (size_t)b * L_ * L_;
    float* Stb = St + (size_t)b * L_ * L_;
#pragma unroll
    for (int mi = 0; mi < 4; ++mi)
#pragma unroll
        for (int ni = 0; ni < 4; ++ni) {
            int i = i0 + wm + mi * 16 + q * 4;
            int j = j0 + wn + ni * 16 + lr;
#pragma unroll
            for (int r4 = 0; r4 < 4; ++r4)
                Sb[(size_t)(i + r4) * L_ + j] = acc[mi][ni][r4];
            *(f32x4*)&Stb[(size_t)j * L_ + i] = acc[mi][ni];  // S^T, contiguous 16B
        }
}

// ---------------------------------------------------------------------------
// row softmax, one wave per row, no barriers: P[row] = fp16(exp(S-max)/sum).
// Covers S rows and S^T rows in one dispatch (contiguous buffers).
// ---------------------------------------------------------------------------
__global__ __launch_bounds__(256) void softmax_rows(const float* __restrict__ S,
                                                    u16* __restrict__ P) {
    const int row = blockIdx.x * 4 + (threadIdx.x >> 6);
    const int lane = threadIdx.x & 63;
    const float* Sr = S + (size_t)row * L_;
    f32x4 a = *(const f32x4*)(Sr + lane * 8);
    f32x4 b = *(const f32x4*)(Sr + lane * 8 + 4);
    float m = fmaxf(fmaxf(fmaxf(a[0], a[1]), fmaxf(a[2], a[3])),
                    fmaxf(fmaxf(b[0], b[1]), fmaxf(b[2], b[3])));
#pragma unroll
    for (int off = 32; off > 0; off >>= 1) m = fmaxf(m, __shfl_xor(m, off));
    float e[8];
    e[0] = __expf(a[0] - m); e[1] = __expf(a[1] - m);
    e[2] = __expf(a[2] - m); e[3] = __expf(a[3] - m);
    e[4] = __expf(b[0] - m); e[5] = __expf(b[1] - m);
    e[6] = __expf(b[2] - m); e[7] = __expf(b[3] - m);
    float s = ((e[0] + e[1]) + (e[2] + e[3])) + ((e[4] + e[5]) + (e[6] + e[7]));
#pragma unroll
    for (int off = 32; off > 0; off >>= 1) s += __shfl_xor(s, off);
    const float inv = 1.0f / s;
    uint4 o;
    o.x = (unsigned)f2h(e[0] * inv) | ((unsigned)f2h(e[1] * inv) << 16);
    o.y = (unsigned)f2h(e[2] * inv) | ((unsigned)f2h(e[3] * inv) << 16);
    o.z = (unsigned)f2h(e[4] * inv) | ((unsigned)f2h(e[5] * inv) << 16);
    o.w = (unsigned)f2h(e[6] * inv) | ((unsigned)f2h(e[7] * inv) << 16);
    *(uint4*)(P + (size_t)row * L_ + lane * 8) = o;
}

// ---------------------------------------------------------------------------
// X = | Oh - P . Vt^T | in fp16, both sides in one dispatch (z = side*32 + b).
// ---------------------------------------------------------------------------
__global__ __launch_bounds__(256, 2) void absdiff_gemm(const u16* __restrict__ Prow,
                                                       const u16* __restrict__ Pcol,
                                                       const u16* __restrict__ JhT,
                                                       const u16* __restrict__ IhT,
                                                       const u16* __restrict__ Ih,
                                                       const u16* __restrict__ Jh,
                                                       u16* __restrict__ Xall) {
    const int z = blockIdx.z;
    const int side = z >> 5, b = z & 31;
    const u16* P = side ? Pcol : Prow;
    const u16* Vt = side ? IhT : JhT;
    const u16* Oh = side ? Jh : Ih;
    u16* Xout = Xall + (size_t)side * B_ * L_ * D_;
    const int i0 = blockIdx.x * 128, d0 = blockIdx.y * 128;
    __shared__ u16 As[128 * 32], Bs[128 * 32];
    const int tid = threadIdx.x;
    const int wave = tid >> 6, lane = tid & 63;
    const int wm = (wave >> 1) * 64, wn = (wave & 1) * 64;
    const int lr = lane & 15, q = lane >> 4;
    const u16* Pb = P + (size_t)b * L_ * L_;
    const u16* Vtb = Vt + (size_t)b * D_ * L_;

    f32x4 acc[4][4] = {};

    for (int k0 = 0; k0 < L_; k0 += 32) {
#pragma unroll
        for (int h = 0; h < 2; ++h) {
            int g = wave * 2 + h;
            int r = g * 16 + (lane >> 2);
            int cg = SW(r, lane & 3);
            async_cp16(Pb + (size_t)(i0 + r) * L_ + k0 + cg * 8, (char*)As + g * 1024);
            async_cp16(Vtb + (size_t)(d0 + r) * L_ + k0 + cg * 8, (char*)Bs + g * 1024);
        }
        __syncthreads();
        half8 af[4], bf[4];
#pragma unroll
        for (int mi = 0; mi < 4; ++mi) {
            int r = wm + mi * 16 + lr;
            af[mi] = *(const half8*)&As[r * 32 + SW(r, q) * 8];
        }
#pragma unroll
        for (int ni = 0; ni < 4; ++ni) {
            int r = wn + ni * 16 + lr;
            bf[ni] = *(const half8*)&Bs[r * 32 + SW(r, q) * 8];
        }
#pragma unroll
        for (int mi = 0; mi < 4; ++mi)
#pragma unroll
            for (int ni = 0; ni < 4; ++ni)
                acc[mi][ni] = __builtin_amdgcn_mfma_f32_16x16x32_f16(af[mi], bf[ni], acc[mi][ni], 0, 0, 0);
        __syncthreads();
    }

    const u16* Ob = Oh + (size_t)b * L_ * D_;
    u16* Xb = Xout + (size_t)b * L_ * D_;
#pragma unroll
    for (int mi = 0; mi < 4; ++mi)
#pragma unroll
        for (int ni = 0; ni < 4; ++ni) {
            int i = i0 + wm + mi * 16 + q * 4;
            int d = d0 + wn + ni * 16 + lr;
#pragma unroll
            for (int r4 = 0; r4 < 4; ++r4) {
                float x = fabsf(h2f(Ob[(size_t)(i + r4) * D_ + d]) - acc[mi][ni][r4]);
                Xb[(size_t)(i + r4) * D_ + d] = f2h(x);
            }
        }
}

// ---------------------------------------------------------------------------
// agg: out[b,h] += (0.5/L) * sum_l tanh( X[l,:].W[:,h] + bias[h] )
// ---------------------------------------------------------------------------
__global__ __launch_bounds__(256, 2) void agg_mfma(const u16* __restrict__ Xall,
                                                   const u16* __restrict__ Wt,
                                                   const float* __restrict__ bias,
                                                   float* __restrict__ out) {
    const int z = blockIdx.z;  // 0..63
    const int bb = z & 31;
    const u16* Xb = Xall + (size_t)z * L_ * D_;
    const int l0 = blockIdx.x * 128, h0 = blockIdx.y * 128;
    __shared__ u16 As[128 * 32], Bs[128 * 32];
    const int tid = threadIdx.x;
    const int wave = tid >> 6, lane = tid & 63;
    const int wm = (wave >> 1) * 64, wn = (wave & 1) * 64;
    const int lr = lane & 15, q = lane >> 4;

    f32x4 acc[4][4] = {};

    for (int k0 = 0; k0 < D_; k0 += 32) {
#pragma unroll
        for (int h = 0; h < 2; ++h) {
            int g = wave * 2 + h;
            int r = g * 16 + (lane >> 2);
            int cg = SW(r, lane & 3);
            async_cp16(Xb + (size_t)(l0 + r) * D_ + k0 + cg * 8, (char*)As + g * 1024);
            async_cp16(Wt + (size_t)(h0 + r) * D_ + k0 + cg * 8, (char*)Bs + g * 1024);
        }
        __syncthreads();
        half8 af[4], bf[4];
#pragma unroll
        for (int mi = 0; mi < 4; ++mi) {
            int r = wm + mi * 16 + lr;
            af[mi] = *(const half8*)&As[r * 32 + SW(r, q) * 8];
        }
#pragma unroll
        for (int ni = 0; ni < 4; ++ni) {
            int r = wn + ni * 16 + lr;
            bf[ni] = *(const half8*)&Bs[r * 32 + SW(r, q) * 8];
        }
#pragma unroll
        for (int mi = 0; mi < 4; ++mi)
#pragma unroll
            for (int ni = 0; ni < 4; ++ni)
                acc[mi][ni] = __builtin_amdgcn_mfma_f32_16x16x32_f16(af[mi], bf[ni], acc[mi][ni], 0, 0, 0);
        __syncthreads();
    }

#pragma unroll
    for (int ni = 0; ni < 4; ++ni) {
        int hcol = h0 + wn + ni * 16 + lr;
        float bsv = bias[hcol];
        float ssum = 0.f;
#pragma unroll
        for (int mi = 0; mi < 4; ++mi)
#pragma unroll
            for (int r4 = 0; r4 < 4; ++r4)
                ssum += tanhf(acc[mi][ni][r4] + bsv);
        ssum += __shfl_xor(ssum, 16);
        ssum += __shfl_xor(ssum, 32);
        if (q == 0) atomicAdd(&out[bb * H_ + hcol], ssum * (0.5f / (float)L_));
    }
}

extern "C" void kernel_launch(void* const* d_in, const int* in_sizes, int n_in,
                              void* d_out, int out_size, void* d_ws, size_t ws_size,
                              hipStream_t stream) {
    const float* I = (const float*)d_in[0];
    const float* Jm = (const float*)d_in[1];
    const float* W = (const float*)d_in[2];
    const float* bias = (const float*)d_in[3];
    float* out = (float*)d_out;

    const size_t BLD = (size_t)B_ * L_ * D_;
    const size_t BLL = (size_t)B_ * L_ * L_;

    char* p = (char*)d_ws;
    auto give = [&](size_t bytes) {
        char* r = p;
        p += (bytes + 255) & ~(size_t)255;
        return r;
    };
    u16* Ih = (u16*)give(BLD * 2);
    u16* Jh = (u16*)give(BLD * 2);
    u16* IhT = (u16*)give(BLD * 2);
    u16* JhT = (u16*)give(BLD * 2);
    u16* WT = (u16*)give((size_t)D_ * H_ * 2);
    float* S = (float*)give(2 * BLL * 4);  // S then St contiguous; Xall aliases later
    float* St = S + BLL;
    u16* Pblk = (u16*)give(2 * BLL * 2);   // Prow then Pcol
    u16* Prow = Pblk;
    u16* Pcol = Pblk + BLL;
    u16* Xall = (u16*)S;                   // aliases S/St (dead after softmax)

    cvt_all<<<dim3(8, 8, 65), 256, 0, stream>>>(I, Jm, W, Ih, IhT, Jh, JhT, WT, out);
    score_mfma<<<dim3(4, 4, B_), 256, 0, stream>>>(Ih, Jh, S, St);
    softmax_rows<<<2 * B_ * L_ / 4, 256, 0, stream>>>(S, Prow);  // S and St rows
    absdiff_gemm<<<dim3(4, 4, 2 * B_), 256, 0, stream>>>(Prow, Pcol, JhT, IhT, Ih, Jh, Xall);
    agg_mfma<<<dim3(4, 4, 2 * B_), 256, 0, stream>>>(Xall, WT, bias, out);
}